// Round 5
// baseline (39.082 us; speedup 1.0000x reference)
//
#include <hip/hip_runtime.h>
#include <math.h>

#define NH 4    // heads
#define DH 8    // head dim
#define NF 64   // F
#define NT 12   // T
#define NB 2    // batch

// Branchless exact-gelu: x * 0.5 * (1 + erf(x/sqrt(2))).
// erf via Abramowitz-Stegun 7.1.26 (max abs err 1.5e-7), no divergence.
// R4 A/B: numerically equivalent to OCML erff at output precision (absmax
// identical), and VALU is fully hidden under memory either way.
__device__ __forceinline__ float gelu_f(float x) {
    const float s = x * 0.70710678118654752440f;
    const float z = __builtin_fabsf(s);
    const float t = __builtin_amdgcn_rcpf(fmaf(0.3275911f, z, 1.0f));
    float p = fmaf(1.061405429f, t, -1.453152027f);
    p = fmaf(p, t, 1.421413741f);
    p = fmaf(p, t, -0.284496736f);
    p = fmaf(p, t, 0.254829592f);
    p *= t;
    const float e = __builtin_amdgcn_exp2f(z * z * -1.44269504088896340736f); // exp(-z^2)
    const float erfa = fmaf(-p, e, 1.0f);                      // erf(|s|)
    const float erfv = __builtin_copysignf(erfa, s);           // erf(s)
    return 0.5f * x * (1.0f + erfv);
}

// One wave (64 lanes) per (b,n) row; lane = f.
// Computes sqT[(b*NH+h)*N + n] and skT[...] (transposed layout for score_kernel).
__global__ __launch_bounds__(256) void qk_kernel(
    const float* __restrict__ x, const float* __restrict__ w1,
    const float* __restrict__ W2, const float* __restrict__ a,
    float* __restrict__ sqT, float* __restrict__ skT, int N)
{
    __shared__ float Wq[NF][NH + 1];
    __shared__ float Wk[NF][NH + 1];
    const int t = threadIdx.x;

    // Fold W2 (64x32) with aq/ak (8 each) -> Wq/Wk (64x4), once per block.
    {
        int f = t >> 2, h = t & 3;
        float accq = 0.f, acck = 0.f;
        #pragma unroll
        for (int k = 0; k < DH; ++k) {
            float w = W2[f * (NH * DH) + h * DH + k];
            accq += w * a[k];
            acck += w * a[DH + k];
        }
        Wq[f][h] = accq;
        Wk[f][h] = acck;
    }
    __syncthreads();

    float w1r[NT];
    #pragma unroll
    for (int i = 0; i < NT; ++i) w1r[i] = w1[i];

    const int wave = t >> 6;
    const int lane = t & 63;                      // = f
    const long long row = (long long)blockIdx.x * 4 + wave;   // in [0, NB*N)
    if (row >= (long long)NB * N) return;

    const float* xr = x + row * (NF * NT) + (long long)lane * NT;
    float4 v0 = *(const float4*)(xr);
    float4 v1 = *(const float4*)(xr + 4);
    float4 v2 = *(const float4*)(xr + 8);
    float dot = v0.x*w1r[0] + v0.y*w1r[1] + v0.z*w1r[2]  + v0.w*w1r[3]
              + v1.x*w1r[4] + v1.y*w1r[5] + v1.z*w1r[6]  + v1.w*w1r[7]
              + v2.x*w1r[8] + v2.y*w1r[9] + v2.z*w1r[10] + v2.w*w1r[11];
    float q = gelu_f(dot);

    float acc[8];
    #pragma unroll
    for (int h = 0; h < NH; ++h) {
        acc[h]     = q * Wq[lane][h];
        acc[4 + h] = q * Wk[lane][h];
    }
    #pragma unroll
    for (int ofs = 32; ofs > 0; ofs >>= 1) {
        #pragma unroll
        for (int i = 0; i < 8; ++i)
            acc[i] += __shfl_xor(acc[i], ofs, 64);
    }
    if (lane < 8) {
        int h   = lane & 3;
        int isK = lane >> 2;
        int b   = (int)(row / N);
        int n   = (int)(row % N);
        float* dst = isK ? skT : sqT;
        dst[((long long)b * NH + h) * N + n] = acc[lane];
    }
}

// R5 restructure: bh lives in blockIdx (uniform per block) so every block
// writes ONE contiguous 4KB chunk and the global write pattern is linear
// per bh-region (vs 8 interleaved streams 16MB apart per wave in R0-R4).
// adj is re-read once per bh, but it's L3/L2-resident (16.8MB), so HBM
// FETCH stays ~one adj pass. i is wave-uniform (nq % 256 == 0 at N=2048).
__global__ __launch_bounds__(256) void score_kernel(
    const float* __restrict__ adj, const float* __restrict__ sqT,
    const float* __restrict__ skT, const float* __restrict__ a,
    float* __restrict__ out, int N)
{
    const float aadj = a[2 * DH];
    const int nq = N >> 2;                          // j-quads per row
    const int blocks_per_bh = (N * nq) >> 8;        // (N*nq)/256
    const int bh = blockIdx.x / blocks_per_bh;      // uniform per block
    const int within = blockIdx.x - bh * blocks_per_bh;
    const int lin = (within << 8) + threadIdx.x;    // in [0, N*nq)
    const int i  = lin / nq;                        // uniform per block
    const int j0 = (lin - i * nq) << 2;

    const float sq = sqT[(long long)bh * N + i];    // scalar broadcast
    float4 sk4 = *(const float4*)(skT + (long long)bh * N + j0);
    float4 adj4 = *(const float4*)(adj + (long long)i * N + j0);

    float4 o;
    o.x = gelu_f(sq + sk4.x + adj4.x * aadj);
    o.y = gelu_f(sq + sk4.y + adj4.y * aadj);
    o.z = gelu_f(sq + sk4.z + adj4.z * aadj);
    o.w = gelu_f(sq + sk4.w + adj4.w * aadj);
    *(float4*)(out + ((long long)bh * N + i) * N + j0) = o;
}

extern "C" void kernel_launch(void* const* d_in, const int* in_sizes, int n_in,
                              void* d_out, int out_size, void* d_ws, size_t ws_size,
                              hipStream_t stream)
{
    const float* x   = (const float*)d_in[0];
    const float* adj = (const float*)d_in[1];
    const float* w1  = (const float*)d_in[2];
    const float* W2  = (const float*)d_in[3];
    const float* a   = (const float*)d_in[4];
    float* out = (float*)d_out;

    // N from adj (N*N elements); B fixed at 2 per reference setup.
    int N = 1;
    while ((long long)(N + 1) * (N + 1) <= (long long)in_sizes[1]) ++N;

    float* sqT = (float*)d_ws;                 // NB*NH*N floats
    float* skT = sqT + (size_t)NB * NH * N;    // NB*NH*N floats

    const int rows = NB * N;                   // one wave per row, 4 waves/block
    qk_kernel<<<(rows + 3) / 4, 256, 0, stream>>>(x, w1, W2, a, sqT, skT, N);

    const int nq = N >> 2;
    const int blocks_per_bh = (N * nq) >> 8;
    score_kernel<<<NB * NH * blocks_per_bh, 256, 0, stream>>>(adj, sqT, skT, a, out, N);
}

// Round 6
// 35.463 us; speedup vs baseline: 1.1020x; 1.1020x over previous
//
#include <hip/hip_runtime.h>
#include <math.h>

#define NH 4    // heads
#define DH 8    // head dim
#define NF 64   // F
#define NT 12   // T
#define NB 2    // batch

// Branchless exact-gelu: x * 0.5 * (1 + erf(x/sqrt(2))).
// erf via Abramowitz-Stegun 7.1.26 (max abs err 1.5e-7), no divergence.
// R0 vs R2 A/B: identical absmax & time vs OCML erff; VALU fully hidden.
__device__ __forceinline__ float gelu_f(float x) {
    const float s = x * 0.70710678118654752440f;
    const float z = __builtin_fabsf(s);
    const float t = __builtin_amdgcn_rcpf(fmaf(0.3275911f, z, 1.0f));
    float p = fmaf(1.061405429f, t, -1.453152027f);
    p = fmaf(p, t, 1.421413741f);
    p = fmaf(p, t, -0.284496736f);
    p = fmaf(p, t, 0.254829592f);
    p *= t;
    const float e = __builtin_amdgcn_exp2f(z * z * -1.44269504088896340736f); // exp(-z^2)
    const float erfa = fmaf(-p, e, 1.0f);                      // erf(|s|)
    const float erfv = __builtin_copysignf(erfa, s);           // erf(s)
    return 0.5f * x * (1.0f + erfv);
}

// One wave (64 lanes) per (b,n) row; lane = f.
// Computes sqT[(b*NH+h)*N + n] and skT[...] (transposed layout for score_kernel).
__global__ __launch_bounds__(256) void qk_kernel(
    const float* __restrict__ x, const float* __restrict__ w1,
    const float* __restrict__ W2, const float* __restrict__ a,
    float* __restrict__ sqT, float* __restrict__ skT, int N)
{
    __shared__ float Wq[NF][NH + 1];
    __shared__ float Wk[NF][NH + 1];
    const int t = threadIdx.x;

    // Fold W2 (64x32) with aq/ak (8 each) -> Wq/Wk (64x4), once per block.
    {
        int f = t >> 2, h = t & 3;
        float accq = 0.f, acck = 0.f;
        #pragma unroll
        for (int k = 0; k < DH; ++k) {
            float w = W2[f * (NH * DH) + h * DH + k];
            accq += w * a[k];
            acck += w * a[DH + k];
        }
        Wq[f][h] = accq;
        Wk[f][h] = acck;
    }
    __syncthreads();

    float w1r[NT];
    #pragma unroll
    for (int i = 0; i < NT; ++i) w1r[i] = w1[i];

    const int wave = t >> 6;
    const int lane = t & 63;                      // = f
    const long long row = (long long)blockIdx.x * 4 + wave;   // in [0, NB*N)
    if (row >= (long long)NB * N) return;

    const float* xr = x + row * (NF * NT) + (long long)lane * NT;
    float4 v0 = *(const float4*)(xr);
    float4 v1 = *(const float4*)(xr + 4);
    float4 v2 = *(const float4*)(xr + 8);
    float dot = v0.x*w1r[0] + v0.y*w1r[1] + v0.z*w1r[2]  + v0.w*w1r[3]
              + v1.x*w1r[4] + v1.y*w1r[5] + v1.z*w1r[6]  + v1.w*w1r[7]
              + v2.x*w1r[8] + v2.y*w1r[9] + v2.z*w1r[10] + v2.w*w1r[11];
    float q = gelu_f(dot);

    float acc[8];
    #pragma unroll
    for (int h = 0; h < NH; ++h) {
        acc[h]     = q * Wq[lane][h];
        acc[4 + h] = q * Wk[lane][h];
    }
    #pragma unroll
    for (int ofs = 32; ofs > 0; ofs >>= 1) {
        #pragma unroll
        for (int i = 0; i < 8; ++i)
            acc[i] += __shfl_xor(acc[i], ofs, 64);
    }
    if (lane < 8) {
        int h   = lane & 3;
        int isK = lane >> 2;
        int b   = (int)(row / N);
        int n   = (int)(row % N);
        float* dst = isK ? skT : sqT;
        dst[((long long)b * NH + h) * N + n] = acc[lane];
    }
}

// R6: R4 structure (adj read ONCE from HBM into registers, reused for all
// 8 bh output streams), but each block owns 512 consecutive quads (8KB of
// a row) and each thread handles two quads 256 quads (1KB) apart. Each
// store instruction remains a full 1KB wave-contiguous burst; each block
// now writes an 8KB contiguous run per bh stream (8x longer than R4).
__global__ __launch_bounds__(256) void score_kernel(
    const float* __restrict__ adj, const float* __restrict__ sqT,
    const float* __restrict__ skT, const float* __restrict__ a,
    float* __restrict__ out, int N)
{
    const float aadj = a[2 * DH];
    const int nq = N >> 2;                          // j-quads per row
    const long long total = (long long)N * nq;
    const long long lin0 = ((long long)blockIdx.x << 9) + threadIdx.x;
    const long long lin1 = lin0 + 256;
    if (lin0 >= total) return;
    const int i0 = (int)(lin0 / nq), j0 = (int)(lin0 - (long long)i0 * nq) << 2;
    const int i1 = (int)(lin1 / nq), j1 = (int)(lin1 - (long long)i1 * nq) << 2;
    const bool doB = (lin1 < total);

    float4 adjA = *(const float4*)(adj + (long long)i0 * N + j0);
    const float aA0 = adjA.x * aadj, aA1 = adjA.y * aadj,
                aA2 = adjA.z * aadj, aA3 = adjA.w * aadj;
    float aB0 = 0.f, aB1 = 0.f, aB2 = 0.f, aB3 = 0.f;
    if (doB) {
        float4 adjB = *(const float4*)(adj + (long long)i1 * N + j1);
        aB0 = adjB.x * aadj; aB1 = adjB.y * aadj;
        aB2 = adjB.z * aadj; aB3 = adjB.w * aadj;
    }

    #pragma unroll
    for (int bh = 0; bh < NB * NH; ++bh) {
        const float sqA = sqT[(long long)bh * N + i0];
        float4 skA = *(const float4*)(skT + (long long)bh * N + j0);
        float4 oA;
        oA.x = gelu_f(sqA + skA.x + aA0);
        oA.y = gelu_f(sqA + skA.y + aA1);
        oA.z = gelu_f(sqA + skA.z + aA2);
        oA.w = gelu_f(sqA + skA.w + aA3);
        *(float4*)(out + ((long long)bh * N + i0) * N + j0) = oA;

        if (doB) {
            const float sqB = sqT[(long long)bh * N + i1];
            float4 skB = *(const float4*)(skT + (long long)bh * N + j1);
            float4 oB;
            oB.x = gelu_f(sqB + skB.x + aB0);
            oB.y = gelu_f(sqB + skB.y + aB1);
            oB.z = gelu_f(sqB + skB.z + aB2);
            oB.w = gelu_f(sqB + skB.w + aB3);
            *(float4*)(out + ((long long)bh * N + i1) * N + j1) = oB;
        }
    }
}

extern "C" void kernel_launch(void* const* d_in, const int* in_sizes, int n_in,
                              void* d_out, int out_size, void* d_ws, size_t ws_size,
                              hipStream_t stream)
{
    const float* x   = (const float*)d_in[0];
    const float* adj = (const float*)d_in[1];
    const float* w1  = (const float*)d_in[2];
    const float* W2  = (const float*)d_in[3];
    const float* a   = (const float*)d_in[4];
    float* out = (float*)d_out;

    // N from adj (N*N elements); B fixed at 2 per reference setup.
    int N = 1;
    while ((long long)(N + 1) * (N + 1) <= (long long)in_sizes[1]) ++N;

    float* sqT = (float*)d_ws;                 // NB*NH*N floats
    float* skT = sqT + (size_t)NB * NH * N;    // NB*NH*N floats

    const int rows = NB * N;                   // one wave per row, 4 waves/block
    qk_kernel<<<(rows + 3) / 4, 256, 0, stream>>>(x, w1, W2, a, sqT, skT, N);

    const long long total = (long long)N * (N >> 2);
    const int blocks = (int)((total + 511) / 512);   // 512 quads per block
    score_kernel<<<blocks, 256, 0, stream>>>(adj, sqT, skT, a, out, N);
}